// Round 16
// baseline (111.259 us; speedup 1.0000x reference)
//
#include <hip/hip_runtime.h>
#include <math.h>

#define IN_N   1024
#define NROWS  8192      // rows per tensor
#define NTOT   16384     // both tensors
#define FFT_N  2046

typedef unsigned short u16;
typedef __attribute__((ext_vector_type(8))) __bf16 bf16x8;
typedef __attribute__((ext_vector_type(4))) float  f32x4;

// ---- bf16 helpers (RTNE) --------------------------------------------------
__device__ __forceinline__ u16 f2bf(float f) {
    unsigned u = __builtin_bit_cast(unsigned, f);
    unsigned r = (u + 0x7fffu + ((u >> 16) & 1u)) >> 16;
    return (u16)r;
}
__device__ __forceinline__ float bf2f(u16 h) {
    unsigned u = ((unsigned)h) << 16;
    return __builtin_bit_cast(float, u);
}

// ---- async global->LDS, 16B per lane (dest = wave-uniform base + lane*16) --
__device__ __forceinline__ void gload_lds16(const void* g, void* l) {
    __builtin_amdgcn_global_load_lds(
        (__attribute__((address_space(1))) void*)g,
        (__attribute__((address_space(3))) void*)l, 16, 0, 0);
}

// ---------------------------------------------------------------------------
// Kernel 1 (fused): blocks 0..1023 build twiddle tables; the rest convert X.
// Memory-floor bound (160MB traffic ~= 25us).
// ---------------------------------------------------------------------------
__global__ __launch_bounds__(256) void prep_kernel(
    const float* __restrict__ pred, const float* __restrict__ tgt,
    u16* __restrict__ Wc, u16* __restrict__ Ws, u16* __restrict__ Xh) {
    int bid = blockIdx.x;
    if (bid < 1024) {
        int k = bid;
        int n0 = threadIdx.x * 4;
        const float c = 6.28318530717958647692f / 2046.0f;
        ushort4 oc, os;
        #pragma unroll
        for (int i = 0; i < 4; ++i) {
            int n = n0 + i;
            int m = (k * n) % FFT_N;
            float a = (float)m * c;
            float sv, cv;
            __sincosf(a, &sv, &cv);
            ((u16*)&oc)[i] = f2bf(cv);
            ((u16*)&os)[i] = f2bf(sv);
        }
        size_t o = (size_t)k * IN_N + n0;
        *(ushort4*)(Wc + o) = oc;
        *(ushort4*)(Ws + o) = os;
    } else {
        size_t gid = (size_t)(bid - 1024) * 256 + threadIdx.x;   // float4 index
        size_t e = gid * 4;
        const size_t half = (size_t)NROWS * IN_N;
        const float* s = (e < half) ? (pred + e) : (tgt + (e - half));
        float4 v = *(const float4*)s;
        ushort4 o;
        o.x = f2bf(v.x); o.y = f2bf(v.y); o.z = f2bf(v.z); o.w = f2bf(v.w);
        *(ushort4*)(Xh + e) = o;
    }
}

// ---------------------------------------------------------------------------
// Kernel 2: MFMA DFT + |.|^2.  R16: the CLEAN two-independent-blocks test.
// 4-wave blocks (256 thr), 128x128 tile; LDS 2 buffers x 24KB = 48KB; regs
// ~230 <= 256 -> TWO blocks co-reside per CU (2 waves/SIMD from DIFFERENT
// barrier domains).  Everything else is R11/R8-identical: per-wave 64x64
// output, 12 b128 frag reads + 32 MFMA per K-tile, X via gload_lds, R5
// swizzle (0 conflicts), R8's proven 2-buffer phase schedule.  Per-CU pipe
// totals are unchanged (reads 73.7Kcyc, MFMA 79.5Kcyc) — block-level desync
// should move time from sum (171K, R11) toward max (~80K).
// R9's confounds (X direct from global, doubled VMEM) are absent.
// ---------------------------------------------------------------------------
#define BM 128
#define BN 128
#define BK 32
#define NKT 32     // K tiles = 1024/32

#define FENCE() asm volatile("" ::: "memory")

__global__ __launch_bounds__(256, 2) void dft_pdp_mfma(
    const u16* __restrict__ Wc, const u16* __restrict__ Ws,
    const u16* __restrict__ Xh, u16* __restrict__ pdp) {

    // per buffer: A(cos) 8KB | S(sin) 8KB | X 8KB = 24KB; x2 buffers = 48KB
    __shared__ __align__(16) char lds[2][24576];

    // ---- XCD-aware decode (1024 blocks, 8 XCDs, bijective):
    // 8 m-blocks of one r-block land co-XCD -> X panel fetched once per XCD.
    const int bid  = blockIdx.x;
    const int xcd  = bid & 7;
    const int slot = bid >> 3;                  // 0..127
    const int m0 = (slot & 7) * BM;
    const int r0 = (xcd * 16 + (slot >> 3)) * BN;

    const int t    = threadIdx.x;
    const int w    = t >> 6;                    // 0..3
    const int lane = t & 63;
    const int wm = (w & 1) * 64;                // wave m offset
    const int wr = (w >> 1) * 64;               // wave r offset
    const int lr = lane & 15;                   // frag row within 16
    // read-side swizzle (R5, conflicts measured 0): slot = g ^ ((row>>1)&3)
    const int rdoff = (((lane >> 4) ^ ((lane >> 1) & 3)) << 4);

    // staging source pre-swizzle (rule 21): thread t -> LDS row t>>2, slot t&3
    // (one gload_lds issue covers 64 rows = 4KB with 256 threads)
    const int srow  = t >> 2;                   // 0..63
    const int sslot = (t & 3) ^ ((t >> 3) & 3);
    const size_t aOfs0 = (size_t)(m0 + srow) * 2048 + sslot * 16;
    const size_t aOfs1 = aOfs0 + (size_t)64 * 2048;
    const size_t xOfs0 = (size_t)(r0 + srow) * 2048 + sslot * 16;
    const size_t xOfs1 = xOfs0 + (size_t)64 * 2048;
    const int woff = w << 10;                   // wave-uniform LDS base part

    f32x4 accRe[4][4], accIm[4][4];
    #pragma unroll
    for (int i = 0; i < 4; ++i)
        #pragma unroll
        for (int j = 0; j < 4; ++j)
            #pragma unroll
            for (int q = 0; q < 4; ++q) { accRe[i][j][q] = 0.f; accIm[i][j][q] = 0.f; }

    #define STAGE_AS(buf, kt) do { \
        gload_lds16((const char*)Wc + aOfs0 + (size_t)(kt) * 64, &lds[buf][0] + woff); \
        gload_lds16((const char*)Wc + aOfs1 + (size_t)(kt) * 64, &lds[buf][0] + 4096 + woff); \
        gload_lds16((const char*)Ws + aOfs0 + (size_t)(kt) * 64, &lds[buf][0] + 8192 + woff); \
        gload_lds16((const char*)Ws + aOfs1 + (size_t)(kt) * 64, &lds[buf][0] + 12288 + woff); \
    } while (0)
    #define STAGE_X(buf, kt) do { \
        gload_lds16((const char*)Xh + xOfs0 + (size_t)(kt) * 64, &lds[buf][0] + 16384 + woff); \
        gload_lds16((const char*)Xh + xOfs1 + (size_t)(kt) * 64, &lds[buf][0] + 20480 + woff); \
    } while (0)
    // fragment loads (byte offsets in one 24KB buffer)
    #define LDA(buf, off)  (*(const bf16x8*)(&lds[buf][0] + (wm + (off) + lr) * 64 + rdoff))
    #define LDSN(buf, off) (*(const bf16x8*)(&lds[buf][0] + 8192 + (wm + (off) + lr) * 64 + rdoff))
    #define LDX(buf, j)    (*(const bf16x8*)(&lds[buf][0] + 16384 + (wr + (j) * 16 + lr) * 64 + rdoff))

    bf16x8 fb0, fb1, fb2, fb3, fa0, fa1, fa2, fa3, fs0, fs1, fs2, fs3;

    // one 8-MFMA cluster (fixed accumulation order = bit-identical results)
    #define CLUSTER(i, FA, FS) do { \
        accRe[i][0] = __builtin_amdgcn_mfma_f32_16x16x32_bf16(FA, fb0, accRe[i][0], 0, 0, 0); \
        accIm[i][0] = __builtin_amdgcn_mfma_f32_16x16x32_bf16(FS, fb0, accIm[i][0], 0, 0, 0); \
        accRe[i][1] = __builtin_amdgcn_mfma_f32_16x16x32_bf16(FA, fb1, accRe[i][1], 0, 0, 0); \
        accIm[i][1] = __builtin_amdgcn_mfma_f32_16x16x32_bf16(FS, fb1, accIm[i][1], 0, 0, 0); \
        accRe[i][2] = __builtin_amdgcn_mfma_f32_16x16x32_bf16(FA, fb2, accRe[i][2], 0, 0, 0); \
        accIm[i][2] = __builtin_amdgcn_mfma_f32_16x16x32_bf16(FS, fb2, accIm[i][2], 0, 0, 0); \
        accRe[i][3] = __builtin_amdgcn_mfma_f32_16x16x32_bf16(FA, fb3, accRe[i][3], 0, 0, 0); \
        accIm[i][3] = __builtin_amdgcn_mfma_f32_16x16x32_bf16(FS, fb3, accIm[i][3], 0, 0, 0); \
    } while (0)

    // ---- prologue: stage tile 0; confirm; preload fb(0) + fa01/fs01(0)
    STAGE_AS(0, 0); STAGE_X(0, 0);
    asm volatile("s_waitcnt vmcnt(0)" ::: "memory");
    __builtin_amdgcn_s_barrier();
    FENCE();
    fb0 = LDX(0, 0); fb1 = LDX(0, 1); fb2 = LDX(0, 2); fb3 = LDX(0, 3);
    fa0 = LDA(0, 0); fa1 = LDA(0, 16); fs0 = LDSN(0, 0); fs1 = LDSN(0, 16);

    for (int kt = 0; kt < NKT; ++kt) {
        const int cur = kt & 1;
        const int nb  = cur ^ 1;
        const bool more = (kt + 1) < NKT;

        // ===== phase A: issue R_B(kt) reads + next A/S stage, compute half 1
        fa2 = LDA(cur, 32); fa3 = LDA(cur, 48);
        fs2 = LDSN(cur, 32); fs3 = LDSN(cur, 48);
        if (more) STAGE_AS(nb, kt + 1);
        asm volatile("s_waitcnt lgkmcnt(4)" ::: "memory");   // boundary preloads done
        __builtin_amdgcn_sched_barrier(0);
        __builtin_amdgcn_s_setprio(1);
        CLUSTER(0, fa0, fs0);
        CLUSTER(1, fa1, fs1);
        __builtin_amdgcn_s_setprio(0);

        // ===== phase B: next X stage, compute half 2
        if (more) STAGE_X(nb, kt + 1);
        asm volatile("s_waitcnt lgkmcnt(0)" ::: "memory");   // fa23/fs23 ready
        __builtin_amdgcn_sched_barrier(0);
        __builtin_amdgcn_s_setprio(1);
        CLUSTER(2, fa2, fs2);
        CLUSTER(3, fa3, fs3);
        __builtin_amdgcn_s_setprio(0);

        // ===== boundary: next tile staged by all waves; preload its frags.
        // vmcnt(0) drain hides under the co-resident second block's compute.
        if (more) {
            asm volatile("s_waitcnt vmcnt(0)" ::: "memory");
            __builtin_amdgcn_s_barrier();        // old-buf reads also all drained
            FENCE();
            fb0 = LDX(nb, 0); fb1 = LDX(nb, 1); fb2 = LDX(nb, 2); fb3 = LDX(nb, 3);
            fa0 = LDA(nb, 0); fa1 = LDA(nb, 16);
            fs0 = LDSN(nb, 0); fs1 = LDSN(nb, 16);
        }
    }
    #undef STAGE_AS
    #undef STAGE_X
    #undef CLUSTER
    #undef LDA
    #undef LDSN
    #undef LDX

    // ---- epilogue: pdp[r][m..m+3] = (Re^2+Im^2)/2046^2 as bf16 (8B stores)
    // C/D layout (m89): col = lane&15 (r), row = (lane>>4)*4 + q (m)
    const float inv = 1.0f / ((float)FFT_N * (float)FFT_N);
    #pragma unroll
    for (int i = 0; i < 4; ++i)
        #pragma unroll
        for (int j = 0; j < 4; ++j) {
            int m = m0 + wm + i * 16 + (lane >> 4) * 4;
            int r = r0 + wr + j * 16 + (lane & 15);
            ushort4 o;
            #pragma unroll
            for (int q = 0; q < 4; ++q) {
                float re = accRe[i][j][q], im = accIm[i][j][q];
                ((u16*)&o)[q] = f2bf((re * re + im * im) * inv);
            }
            *(ushort4*)(pdp + (size_t)r * IN_N + m) = o;
        }
}

// ---------------------------------------------------------------------------
// Kernel 3: per-row-pair stats — ONE WAVE per row pair, pure shuffle
// reductions (zero barriers).  Symmetry weights: 2 for k=1..1022, 1 at 0,1023.
// delay = 1023*(1 - w0)  =>  |d_p - d_t|/2046 = 0.5*|w0_p - w0_t|
// ---------------------------------------------------------------------------
__device__ __forceinline__ float wsum(float v) {
    #pragma unroll
    for (int m = 32; m >= 1; m >>= 1) v += __shfl_xor(v, m);
    return v;
}
__device__ __forceinline__ float wmax(float v) {
    #pragma unroll
    for (int m = 32; m >= 1; m >>= 1) v = fmaxf(v, __shfl_xor(v, m));
    return v;
}
__device__ __forceinline__ float wmin(float v) {
    #pragma unroll
    for (int m = 32; m >= 1; m >>= 1) v = fminf(v, __shfl_xor(v, m));
    return v;
}

__global__ __launch_bounds__(256) void row_stats_kernel(
    const u16* __restrict__ pdp,
    float* __restrict__ mse_rows, float* __restrict__ dd_rows) {

    const int wid  = threadIdx.x >> 6;
    const int lane = threadIdx.x & 63;
    const int r = blockIdx.x * 4 + wid;
    const u16* pp = pdp + (size_t)r * IN_N + lane * 16;
    const u16* pt = pdp + (size_t)(NROWS + r) * IN_N + lane * 16;

    uint4 v0 = *(const uint4*)pp;       uint4 v1 = *(const uint4*)(pp + 8);
    uint4 u0 = *(const uint4*)pt;       uint4 u1 = *(const uint4*)(pt + 8);
    float a[16], b[16];
    {
        unsigned pw[8] = {v0.x, v0.y, v0.z, v0.w, v1.x, v1.y, v1.z, v1.w};
        unsigned tw[8] = {u0.x, u0.y, u0.z, u0.w, u1.x, u1.y, u1.z, u1.w};
        #pragma unroll
        for (int i = 0; i < 8; ++i) {
            a[2*i]   = bf2f((u16)(pw[i] & 0xffffu));
            a[2*i+1] = bf2f((u16)(pw[i] >> 16));
            b[2*i]   = bf2f((u16)(tw[i] & 0xffffu));
            b[2*i+1] = bf2f((u16)(tw[i] >> 16));
        }
    }

    float wsp = 0.f, wst = 0.f;
    float mxp = -1e30f, mnp = 1e30f, mxt = -1e30f, mnt = 1e30f;
    #pragma unroll
    for (int i = 0; i < 16; ++i) {
        int k = lane * 16 + i;
        float wgt = (k == 0 || k == 1023) ? 1.f : 2.f;
        wsp += wgt * a[i];        wst += wgt * b[i];
        mxp = fmaxf(mxp, a[i]);   mnp = fminf(mnp, a[i]);
        mxt = fmaxf(mxt, b[i]);   mnt = fminf(mnt, b[i]);
    }
    float Ep  = wsum(wsp);
    float Et  = wsum(wst);
    float Mp  = wmax(mxp);
    float mp_ = wmin(mnp);
    float Mt  = wmax(mxt);
    float mt_ = wmin(mnt);

    float scp = (Ep < 1e-8f) ? 1.f : 1.f / Ep;
    float sct = (Et < 1e-8f) ? 1.f : 1.f / Et;
    float rngp = fmaxf(scp * (Mp - mp_), 1e-8f);
    float rngt = fmaxf(sct * (Mt - mt_), 1e-8f);
    float cfp = 10.f * scp / rngp;        // score_k = cfp * raw_pdp_k
    float cft = 10.f * sct / rngt;
    float smp = cfp * Mp;                 // max score
    float smt = cft * Mt;

    float zp = 0.f, zt = 0.f, ms = 0.f;
    #pragma unroll
    for (int i = 0; i < 16; ++i) {
        int k = lane * 16 + i;
        float wgt = (k == 0 || k == 1023) ? 1.f : 2.f;
        zp += wgt * __expf(cfp * a[i] - smp);
        zt += wgt * __expf(cft * b[i] - smt);
        float d = a[i] * scp - b[i] * sct;
        ms += wgt * d * d;
    }
    float Zp  = wsum(zp);
    float Zt  = wsum(zt);
    float MSE = wsum(ms);

    if (lane == 0) {
        float w0p = __expf(cfp * a[0] - smp) / Zp;   // k=0 lives in lane 0
        float w0t = __expf(cft * b[0] - smt) / Zt;
        mse_rows[r] = MSE;
        dd_rows[r]  = 0.5f * fabsf(w0p - w0t);
    }
}

// ---------------------------------------------------------------------------
// Kernel 4: final scalar reduce.
// ---------------------------------------------------------------------------
__global__ __launch_bounds__(256) void final_kernel(
    const float* __restrict__ mse_rows, const float* __restrict__ dd_rows,
    float* __restrict__ out) {
    __shared__ float r1[256];
    __shared__ float r2[256];
    int t = threadIdx.x;
    float s1 = 0.f, s2 = 0.f;
    for (int r = t; r < NROWS; r += 256) { s1 += mse_rows[r]; s2 += dd_rows[r]; }
    r1[t] = s1; r2[t] = s2;
    __syncthreads();
    for (int s = 128; s > 0; s >>= 1) {
        if (t < s) { r1[t] += r1[t + s]; r2[t] += r2[t + s]; }
        __syncthreads();
    }
    if (t == 0) {
        float mse = r1[0] / ((float)NROWS * (float)FFT_N);
        float dl  = r2[0] / (float)NROWS;
        out[0] = 0.7f * mse + 0.3f * dl;
    }
}

// ---------------------------------------------------------------------------
extern "C" void kernel_launch(void* const* d_in, const int* in_sizes, int n_in,
                              void* d_out, int out_size, void* d_ws, size_t ws_size,
                              hipStream_t stream) {
    const float* pred = (const float*)d_in[0];
    const float* tgt  = (const float*)d_in[1];
    float* out = (float*)d_out;

    char* ws = (char*)d_ws;
    u16* Xh   = (u16*)ws;                                   // 32 MiB
    u16* Wch  = (u16*)(ws + (size_t)32 * 1024 * 1024);      //  2 MiB
    u16* Wsh  = (u16*)(ws + (size_t)34 * 1024 * 1024);      //  2 MiB
    u16* pdp  = (u16*)(ws + (size_t)40 * 1024 * 1024);      // 32 MiB
    float* mse_rows = (float*)(ws + (size_t)72 * 1024 * 1024);
    float* dd_rows  = mse_rows + NROWS;

    prep_kernel<<<1024 + NTOT * IN_N / 4 / 256, 256, 0, stream>>>(pred, tgt, Wch, Wsh, Xh);

    dft_pdp_mfma<<<1024, 256, 0, stream>>>(Wch, Wsh, Xh, pdp);

    row_stats_kernel<<<NROWS / 4, 256, 0, stream>>>(pdp, mse_rows, dd_rows);
    final_kernel<<<1, 256, 0, stream>>>(mse_rows, dd_rows, out);
}

// Round 17
// 110.727 us; speedup vs baseline: 1.0048x; 1.0048x over previous
//
#include <hip/hip_runtime.h>
#include <math.h>

#define IN_N   1024
#define NROWS  8192      // rows per tensor
#define NTOT   16384     // both tensors
#define FFT_N  2046

typedef unsigned short u16;
typedef __attribute__((ext_vector_type(8))) __bf16 bf16x8;
typedef __attribute__((ext_vector_type(4))) float  f32x4;

// ---- bf16 helpers (RTNE) --------------------------------------------------
__device__ __forceinline__ u16 f2bf(float f) {
    unsigned u = __builtin_bit_cast(unsigned, f);
    unsigned r = (u + 0x7fffu + ((u >> 16) & 1u)) >> 16;
    return (u16)r;
}
__device__ __forceinline__ float bf2f(u16 h) {
    unsigned u = ((unsigned)h) << 16;
    return __builtin_bit_cast(float, u);
}

// ---- async global->LDS, 16B per lane (dest = wave-uniform base + lane*16) --
__device__ __forceinline__ void gload_lds16(const void* g, void* l) {
    __builtin_amdgcn_global_load_lds(
        (__attribute__((address_space(1))) void*)g,
        (__attribute__((address_space(3))) void*)l, 16, 0, 0);
}

// ---------------------------------------------------------------------------
// Kernel 1 (fused): blocks 0..1023 build twiddle tables; the rest convert X.
// Memory-floor bound (164MB traffic ~= 26us).
// ---------------------------------------------------------------------------
__global__ __launch_bounds__(256) void prep_kernel(
    const float* __restrict__ pred, const float* __restrict__ tgt,
    u16* __restrict__ Wc, u16* __restrict__ Ws, u16* __restrict__ Xh) {
    int bid = blockIdx.x;
    if (bid < 1024) {
        int k = bid;
        int n0 = threadIdx.x * 4;
        const float c = 6.28318530717958647692f / 2046.0f;
        ushort4 oc, os;
        #pragma unroll
        for (int i = 0; i < 4; ++i) {
            int n = n0 + i;
            int m = (k * n) % FFT_N;
            float a = (float)m * c;
            float sv, cv;
            __sincosf(a, &sv, &cv);
            ((u16*)&oc)[i] = f2bf(cv);
            ((u16*)&os)[i] = f2bf(sv);
        }
        size_t o = (size_t)k * IN_N + n0;
        *(ushort4*)(Wc + o) = oc;
        *(ushort4*)(Ws + o) = os;
    } else {
        size_t gid = (size_t)(bid - 1024) * 256 + threadIdx.x;   // float4 index
        size_t e = gid * 4;
        const size_t half = (size_t)NROWS * IN_N;
        const float* s = (e < half) ? (pred + e) : (tgt + (e - half));
        float4 v = *(const float4*)s;
        ushort4 o;
        o.x = f2bf(v.x); o.y = f2bf(v.y); o.z = f2bf(v.z); o.w = f2bf(v.w);
        *(ushort4*)(Xh + e) = o;
    }
}

// ---------------------------------------------------------------------------
// Kernel 2: MFMA DFT + |.|^2.  FINAL = R11 structure (empirical best, 70.7us,
// reproduced R15):  4-buffer rotation (128KB LDS), full one-tile-ahead frag
// prefetch, counted vmcnt(4)/lgkm(4), one barrier per tile, R5 XOR swizzle
// (0 conflicts), XCD-bijective decode, 16x16x32 MFMA, 128x256 tile, 8 waves.
//
// Structural floor (7 schedules tested): per-CU per-tile = 1152cyc ds_read
// issue + 1242cyc MFMA, ADDITIVE.  R16's clean 2-independent-blocks test was
// null -> additivity is per-SIMD issue-port serialization of ds_read_b128
// (~12cyc occupancy, m134) vs MFMA, not barrier lockstep; reads-per-MFMA is
// register-capped (acc = 128 AGPR).  R9/R10/R12/R13/R14/R16 all regressed or
// null (see session journal).
// ---------------------------------------------------------------------------
#define BM 128
#define BN 256
#define BK 32
#define NKT 32     // K tiles = 1024/32

#define FENCE() asm volatile("" ::: "memory")

__global__ __launch_bounds__(512, 2) void dft_pdp_mfma(
    const u16* __restrict__ Wc, const u16* __restrict__ Ws,
    const u16* __restrict__ Xh, u16* __restrict__ pdp) {

    // per buffer: A(cos) 8KB | S(sin) 8KB | X 16KB = 32KB; x4 buffers = 128KB
    __shared__ __align__(16) char lds[4][32768];

    // ---- XCD-aware decode (512 blocks, 8 XCDs, bijective)
    const int bid  = blockIdx.x;
    const int xcd  = bid & 7;
    const int slot = bid >> 3;                  // 0..63
    const int m0 = (slot & 7) * BM;
    const int r0 = (xcd * 8 + (slot >> 3)) * BN;

    const int t    = threadIdx.x;
    const int w    = t >> 6;                    // 0..7
    const int lane = t & 63;
    const int wm = (w & 1) * 64;                // wave m offset
    const int wr = (w >> 1) * 64;               // wave r offset
    const int lr = lane & 15;                   // frag row within 16
    // read-side swizzle (R5, conflicts measured 0): slot = g ^ ((row>>1)&3)
    const int rdoff = (((lane >> 4) ^ ((lane >> 1) & 3)) << 4);

    // staging source pre-swizzle (rule 21): thread t -> LDS row t>>2, slot t&3
    const int srow  = t >> 2;                   // 0..127
    const int sslot = (t & 3) ^ ((t >> 3) & 3);
    const size_t aOfs  = (size_t)(m0 + srow) * 2048 + sslot * 16;
    const size_t xOfs0 = (size_t)(r0 + srow) * 2048 + sslot * 16;
    const size_t xOfs1 = (size_t)(r0 + 128 + srow) * 2048 + sslot * 16;
    const int woff = w << 10;                   // wave-uniform LDS base part

    f32x4 accRe[4][4], accIm[4][4];
    #pragma unroll
    for (int i = 0; i < 4; ++i)
        #pragma unroll
        for (int j = 0; j < 4; ++j)
            #pragma unroll
            for (int q = 0; q < 4; ++q) { accRe[i][j][q] = 0.f; accIm[i][j][q] = 0.f; }

    #define STAGE(buf, kt) do { \
        gload_lds16((const char*)Wc + aOfs + (size_t)(kt) * 64, &lds[buf][0] + woff); \
        gload_lds16((const char*)Ws + aOfs + (size_t)(kt) * 64, &lds[buf][0] + 8192 + woff); \
        gload_lds16((const char*)Xh + xOfs0 + (size_t)(kt) * 64, &lds[buf][0] + 16384 + woff); \
        gload_lds16((const char*)Xh + xOfs1 + (size_t)(kt) * 64, &lds[buf][0] + 24576 + woff); \
    } while (0)
    // fragment loads (byte offsets in one 32KB buffer)
    #define LDA(buf, off)  (*(const bf16x8*)(&lds[buf][0] + (wm + (off) + lr) * 64 + rdoff))
    #define LDSN(buf, off) (*(const bf16x8*)(&lds[buf][0] + 8192 + (wm + (off) + lr) * 64 + rdoff))
    #define LDX(buf, j)    (*(const bf16x8*)(&lds[buf][0] + 16384 + (wr + (j) * 16 + lr) * 64 + rdoff))

    bf16x8 fa0, fa1, fa2, fa3, fs0, fs1, fs2, fs3;       // single-buffered
    bf16x8 fbE0, fbE1, fbE2, fbE3, fbO0, fbO1, fbO2, fbO3; // fb double-buffered

    // one 8-MFMA cluster (fixed accumulation order = bit-identical results)
    #define CLUSTER(i, FA, FS, B0, B1, B2, B3) do { \
        accRe[i][0] = __builtin_amdgcn_mfma_f32_16x16x32_bf16(FA, B0, accRe[i][0], 0, 0, 0); \
        accIm[i][0] = __builtin_amdgcn_mfma_f32_16x16x32_bf16(FS, B0, accIm[i][0], 0, 0, 0); \
        accRe[i][1] = __builtin_amdgcn_mfma_f32_16x16x32_bf16(FA, B1, accRe[i][1], 0, 0, 0); \
        accIm[i][1] = __builtin_amdgcn_mfma_f32_16x16x32_bf16(FS, B1, accIm[i][1], 0, 0, 0); \
        accRe[i][2] = __builtin_amdgcn_mfma_f32_16x16x32_bf16(FA, B2, accRe[i][2], 0, 0, 0); \
        accIm[i][2] = __builtin_amdgcn_mfma_f32_16x16x32_bf16(FS, B2, accIm[i][2], 0, 0, 0); \
        accRe[i][3] = __builtin_amdgcn_mfma_f32_16x16x32_bf16(FA, B3, accRe[i][3], 0, 0, 0); \
        accIm[i][3] = __builtin_amdgcn_mfma_f32_16x16x32_bf16(FS, B3, accIm[i][3], 0, 0, 0); \
    } while (0)

    #define TILE(kt, C0, C1, C2, C3, N0, N1, N2, N3) do { \
        const int bn_ = ((kt) + 1) & 3; \
        /* top: confirm STAGE(kt+1); STAGE(kt+2) stays in flight */ \
        if ((kt) <= NKT - 3) asm volatile("s_waitcnt vmcnt(4)" ::: "memory"); \
        else                 asm volatile("s_waitcnt vmcnt(0)" ::: "memory"); \
        __builtin_amdgcn_s_barrier(); \
        FENCE(); \
        if ((kt) + 1 < NKT) {            /* fb(kt+1) into alternate set */ \
            N0 = LDX(bn_, 0); N1 = LDX(bn_, 1); N2 = LDX(bn_, 2); N3 = LDX(bn_, 3); \
        } \
        if ((kt) + 3 < NKT) STAGE(((kt) + 3) & 3, (kt) + 3); \
        if ((kt) + 1 < NKT) asm volatile("s_waitcnt lgkmcnt(4)" ::: "memory"); \
        else                asm volatile("s_waitcnt lgkmcnt(0)" ::: "memory"); \
        __builtin_amdgcn_sched_barrier(0); \
        __builtin_amdgcn_s_setprio(1); \
        CLUSTER(0, fa0, fs0, C0, C1, C2, C3); \
        if ((kt) + 1 < NKT) { fa0 = LDA(bn_, 0);  fs0 = LDSN(bn_, 0);  } \
        CLUSTER(1, fa1, fs1, C0, C1, C2, C3); \
        if ((kt) + 1 < NKT) { fa1 = LDA(bn_, 16); fs1 = LDSN(bn_, 16); } \
        CLUSTER(2, fa2, fs2, C0, C1, C2, C3); \
        if ((kt) + 1 < NKT) { fa2 = LDA(bn_, 32); fs2 = LDSN(bn_, 32); } \
        CLUSTER(3, fa3, fs3, C0, C1, C2, C3); \
        if ((kt) + 1 < NKT) { fa3 = LDA(bn_, 48); fs3 = LDSN(bn_, 48); } \
        __builtin_amdgcn_s_setprio(0); \
    } while (0)

    // ---- prologue: stage tiles 0..2; confirm tile 0; read all frags(0)
    STAGE(0, 0); STAGE(1, 1); STAGE(2, 2);
    asm volatile("s_waitcnt vmcnt(8)" ::: "memory");
    __builtin_amdgcn_s_barrier();
    FENCE();
    fbE0 = LDX(0, 0); fbE1 = LDX(0, 1); fbE2 = LDX(0, 2); fbE3 = LDX(0, 3);
    fa0 = LDA(0, 0);  fa1 = LDA(0, 16); fa2 = LDA(0, 32); fa3 = LDA(0, 48);
    fs0 = LDSN(0, 0); fs1 = LDSN(0, 16); fs2 = LDSN(0, 32); fs3 = LDSN(0, 48);

    for (int kt2 = 0; kt2 < NKT; kt2 += 2) {
        TILE(kt2,     fbE0, fbE1, fbE2, fbE3, fbO0, fbO1, fbO2, fbO3);
        TILE(kt2 + 1, fbO0, fbO1, fbO2, fbO3, fbE0, fbE1, fbE2, fbE3);
    }
    #undef TILE
    #undef CLUSTER
    #undef STAGE
    #undef LDA
    #undef LDSN
    #undef LDX

    // ---- epilogue: pdp[r][m..m+3] = (Re^2+Im^2)/2046^2 as bf16 (8B stores)
    // C/D layout (m89): col = lane&15 (r), row = (lane>>4)*4 + q (m)
    const float inv = 1.0f / ((float)FFT_N * (float)FFT_N);
    #pragma unroll
    for (int i = 0; i < 4; ++i)
        #pragma unroll
        for (int j = 0; j < 4; ++j) {
            int m = m0 + wm + i * 16 + (lane >> 4) * 4;
            int r = r0 + wr + j * 16 + (lane & 15);
            ushort4 o;
            #pragma unroll
            for (int q = 0; q < 4; ++q) {
                float re = accRe[i][j][q], im = accIm[i][j][q];
                ((u16*)&o)[q] = f2bf((re * re + im * im) * inv);
            }
            *(ushort4*)(pdp + (size_t)r * IN_N + m) = o;
        }
}

// ---------------------------------------------------------------------------
// Kernel 3: per-row-pair stats — ONE WAVE per row pair, pure shuffle
// reductions (zero barriers).  Symmetry weights: 2 for k=1..1022, 1 at 0,1023.
// delay = 1023*(1 - w0)  =>  |d_p - d_t|/2046 = 0.5*|w0_p - w0_t|
// ---------------------------------------------------------------------------
__device__ __forceinline__ float wsum(float v) {
    #pragma unroll
    for (int m = 32; m >= 1; m >>= 1) v += __shfl_xor(v, m);
    return v;
}
__device__ __forceinline__ float wmax(float v) {
    #pragma unroll
    for (int m = 32; m >= 1; m >>= 1) v = fmaxf(v, __shfl_xor(v, m));
    return v;
}
__device__ __forceinline__ float wmin(float v) {
    #pragma unroll
    for (int m = 32; m >= 1; m >>= 1) v = fminf(v, __shfl_xor(v, m));
    return v;
}

__global__ __launch_bounds__(256) void row_stats_kernel(
    const u16* __restrict__ pdp,
    float* __restrict__ mse_rows, float* __restrict__ dd_rows) {

    const int wid  = threadIdx.x >> 6;
    const int lane = threadIdx.x & 63;
    const int r = blockIdx.x * 4 + wid;
    const u16* pp = pdp + (size_t)r * IN_N + lane * 16;
    const u16* pt = pdp + (size_t)(NROWS + r) * IN_N + lane * 16;

    uint4 v0 = *(const uint4*)pp;       uint4 v1 = *(const uint4*)(pp + 8);
    uint4 u0 = *(const uint4*)pt;       uint4 u1 = *(const uint4*)(pt + 8);
    float a[16], b[16];
    {
        unsigned pw[8] = {v0.x, v0.y, v0.z, v0.w, v1.x, v1.y, v1.z, v1.w};
        unsigned tw[8] = {u0.x, u0.y, u0.z, u0.w, u1.x, u1.y, u1.z, u1.w};
        #pragma unroll
        for (int i = 0; i < 8; ++i) {
            a[2*i]   = bf2f((u16)(pw[i] & 0xffffu));
            a[2*i+1] = bf2f((u16)(pw[i] >> 16));
            b[2*i]   = bf2f((u16)(tw[i] & 0xffffu));
            b[2*i+1] = bf2f((u16)(tw[i] >> 16));
        }
    }

    float wsp = 0.f, wst = 0.f;
    float mxp = -1e30f, mnp = 1e30f, mxt = -1e30f, mnt = 1e30f;
    #pragma unroll
    for (int i = 0; i < 16; ++i) {
        int k = lane * 16 + i;
        float wgt = (k == 0 || k == 1023) ? 1.f : 2.f;
        wsp += wgt * a[i];        wst += wgt * b[i];
        mxp = fmaxf(mxp, a[i]);   mnp = fminf(mnp, a[i]);
        mxt = fmaxf(mxt, b[i]);   mnt = fminf(mnt, b[i]);
    }
    float Ep  = wsum(wsp);
    float Et  = wsum(wst);
    float Mp  = wmax(mxp);
    float mp_ = wmin(mnp);
    float Mt  = wmax(mxt);
    float mt_ = wmin(mnt);

    float scp = (Ep < 1e-8f) ? 1.f : 1.f / Ep;
    float sct = (Et < 1e-8f) ? 1.f : 1.f / Et;
    float rngp = fmaxf(scp * (Mp - mp_), 1e-8f);
    float rngt = fmaxf(sct * (Mt - mt_), 1e-8f);
    float cfp = 10.f * scp / rngp;        // score_k = cfp * raw_pdp_k
    float cft = 10.f * sct / rngt;
    float smp = cfp * Mp;                 // max score
    float smt = cft * Mt;

    float zp = 0.f, zt = 0.f, ms = 0.f;
    #pragma unroll
    for (int i = 0; i < 16; ++i) {
        int k = lane * 16 + i;
        float wgt = (k == 0 || k == 1023) ? 1.f : 2.f;
        zp += wgt * __expf(cfp * a[i] - smp);
        zt += wgt * __expf(cft * b[i] - smt);
        float d = a[i] * scp - b[i] * sct;
        ms += wgt * d * d;
    }
    float Zp  = wsum(zp);
    float Zt  = wsum(zt);
    float MSE = wsum(ms);

    if (lane == 0) {
        float w0p = __expf(cfp * a[0] - smp) / Zp;   // k=0 lives in lane 0
        float w0t = __expf(cft * b[0] - smt) / Zt;
        mse_rows[r] = MSE;
        dd_rows[r]  = 0.5f * fabsf(w0p - w0t);
    }
}

// ---------------------------------------------------------------------------
// Kernel 4: final scalar reduce.
// ---------------------------------------------------------------------------
__global__ __launch_bounds__(256) void final_kernel(
    const float* __restrict__ mse_rows, const float* __restrict__ dd_rows,
    float* __restrict__ out) {
    __shared__ float r1[256];
    __shared__ float r2[256];
    int t = threadIdx.x;
    float s1 = 0.f, s2 = 0.f;
    for (int r = t; r < NROWS; r += 256) { s1 += mse_rows[r]; s2 += dd_rows[r]; }
    r1[t] = s1; r2[t] = s2;
    __syncthreads();
    for (int s = 128; s > 0; s >>= 1) {
        if (t < s) { r1[t] += r1[t + s]; r2[t] += r2[t + s]; }
        __syncthreads();
    }
    if (t == 0) {
        float mse = r1[0] / ((float)NROWS * (float)FFT_N);
        float dl  = r2[0] / (float)NROWS;
        out[0] = 0.7f * mse + 0.3f * dl;
    }
}

// ---------------------------------------------------------------------------
extern "C" void kernel_launch(void* const* d_in, const int* in_sizes, int n_in,
                              void* d_out, int out_size, void* d_ws, size_t ws_size,
                              hipStream_t stream) {
    const float* pred = (const float*)d_in[0];
    const float* tgt  = (const float*)d_in[1];
    float* out = (float*)d_out;

    char* ws = (char*)d_ws;
    u16* Xh   = (u16*)ws;                                   // 32 MiB
    u16* Wch  = (u16*)(ws + (size_t)32 * 1024 * 1024);      //  2 MiB
    u16* Wsh  = (u16*)(ws + (size_t)34 * 1024 * 1024);      //  2 MiB
    u16* pdp  = (u16*)(ws + (size_t)40 * 1024 * 1024);      // 32 MiB
    float* mse_rows = (float*)(ws + (size_t)72 * 1024 * 1024);
    float* dd_rows  = mse_rows + NROWS;

    prep_kernel<<<1024 + NTOT * IN_N / 4 / 256, 256, 0, stream>>>(pred, tgt, Wch, Wsh, Xh);

    dft_pdp_mfma<<<512, 512, 0, stream>>>(Wch, Wsh, Xh, pdp);

    row_stats_kernel<<<NROWS / 4, 256, 0, stream>>>(pdp, mse_rows, dd_rows);
    final_kernel<<<1, 256, 0, stream>>>(mse_rows, dd_rows, out);
}